// Round 5
// baseline (95.940 us; speedup 1.0000x reference)
//
#include <hip/hip_runtime.h>
#include <math.h>

#define B_ 32
#define C_ 64
#define L_ 16384
#define LT 64                          // l-columns per block tile
#define NBLK (B_ * (L_ / LT))          // 8192 blocks

typedef __attribute__((ext_vector_type(8))) short short8;
typedef __attribute__((ext_vector_type(4))) float f32x4;

__device__ __forceinline__ unsigned short f2bf(float x) {
  unsigned int u = __builtin_bit_cast(unsigned int, x);
  u += 0x7fffu + ((u >> 16) & 1u);   // RNE
  return (unsigned short)(u >> 16);
}

__device__ __forceinline__ float lrelu(float x) {
  return x >= 0.f ? x : 0.1f * x;
}

// ---------------------------------------------------------------------------
// Prep (tiny): kern4[b,c,4] = depthwise kernels (stride-4 padded);
// att[b,c] = sigmoid(lrelu(x1 ca1^T) ca2^T);
// wfrag = conv_w as bf16 MFMA A-fragments in per-lane load order:
//   wfrag[((kt*4+mt)*64 + lane)*8 + j] = bf16(conv_w[mt*16+(lane&15)][kt*32+(lane>>4)*8+j])
// ---------------------------------------------------------------------------
__global__ void da_prep(const float* __restrict__ x1,
                        const float* __restrict__ W1,
                        const float* __restrict__ W2,
                        const float* __restrict__ ca_w1,
                        const float* __restrict__ ca_w2,
                        const float* __restrict__ conv_w,
                        float* __restrict__ kern4,
                        float* __restrict__ att,
                        unsigned short* __restrict__ wfrag) {
  int b = blockIdx.x;      // 32
  int t = threadIdx.x;     // 64
  __shared__ float x1s[64], h[64], a1[8];
  x1s[t] = x1[b * 64 + t];
  __syncthreads();
  {
    const float* w1r = W1 + t * 64;
    float s = 0.f;
    #pragma unroll
    for (int i = 0; i < 64; ++i) s = fmaf(x1s[i], w1r[i], s);
    h[t] = lrelu(s);
  }
  if (t < 8) {
    const float* cw = ca_w1 + t * 64;
    float a = 0.f;
    #pragma unroll
    for (int i = 0; i < 64; ++i) a = fmaf(x1s[i], cw[i], a);
    a1[t] = lrelu(a);
  }
  __syncthreads();
  #pragma unroll
  for (int kk = 0; kk < 3; ++kk) {
    const float* w2r = W2 + (t * 3 + kk) * 64;
    float s2 = 0.f;
    #pragma unroll
    for (int i = 0; i < 64; ++i) s2 = fmaf(h[i], w2r[i], s2);
    kern4[(b * 64 + t) * 4 + kk] = s2;
  }
  kern4[(b * 64 + t) * 4 + 3] = 0.f;
  {
    float a = 0.f;
    #pragma unroll
    for (int r = 0; r < 8; ++r) a = fmaf(a1[r], ca_w2[t * 8 + r], a);
    att[b * 64 + t] = 1.f / (1.f + expf(-a));
  }
  if (b == 0) {
    #pragma unroll
    for (int kt = 0; kt < 2; ++kt)
      #pragma unroll
      for (int mt = 0; mt < 4; ++mt)
        #pragma unroll
        for (int j = 0; j < 8; ++j) {
          float e = conv_w[(mt * 16 + (t & 15)) * 64 + kt * 32 + (t >> 4) * 8 + j];
          wfrag[(((kt * 4 + mt) * 64) + t) * 8 + j] = f2bf(e);
        }
  }
}

// ---------------------------------------------------------------------------
// Main: BARRIER-FREE. One (b, 64-l) tile per block, 8192 blocks.
// Assignment: lane = c, wave = l-quarter. Each wave writes midT rows
// [wave*16, wave*16+16) across all 64 c, and its MFMA B-frags read exactly
// those rows -> all dependencies are intra-wave (compiler lgkmcnt only).
// x0 staged straight to registers; epilogue residual re-reads x0 from L2
// (block's own 16KB guaranteed resident); halo sectors are neighbor blocks'
// payload (L2/L3-absorbed). LDS = 8KB midT only -> 7 blocks/CU, 28 waves.
// midT: halfword idx = l*64 + (c ^ ((l&7)<<3)):
//   writes: one row/instr, 128B contiguous permuted -> conflict-free;
//   b128 reads: 16 l x 4 cb-groups -> 32 words, 2-way max -> free.
// ---------------------------------------------------------------------------
__global__ __launch_bounds__(256, 7) void da_main(
    const float* __restrict__ x0,
    const float* __restrict__ conv_b,
    const float* __restrict__ kern4,
    const float* __restrict__ att,
    const unsigned short* __restrict__ wfrag,
    float* __restrict__ out) {
  __shared__ unsigned short midT[LT * 64];   // 8 KB

  int bid = blockIdx.x;            // 0..8191
  int b = bid >> 8;                // 256 tiles per batch
  int l0 = (bid & 255) * LT;
  int tid = threadIdx.x;
  int lane = tid & 63;
  int wave = tid >> 6;

  int m_lane = lane & 15;          // MFMA row/col within 16
  int kbase = (lane >> 4) * 8;     // MFMA k base
  int qq = lane >> 4;              // C/D row group

  int c = lane;                    // channel owned by this thread
  int gl = l0 + wave * 16;         // this thread's global l base

  // ---- Stage this thread's 16 x0 elements (row c) into registers
  const float* xrow = x0 + ((size_t)(b * 64 + c)) * L_ + gl;
  float4 q0 = ((const float4*)xrow)[0];
  float4 q1 = ((const float4*)xrow)[1];
  float4 q2 = ((const float4*)xrow)[2];
  float4 q3 = ((const float4*)xrow)[3];
  float hp = (gl > 0) ? xrow[-1] : 0.f;          // halo: L2/L3-absorbed
  float hn = (gl + 16 < L_) ? xrow[16] : 0.f;

  // ---- Per-row depthwise kernel taps
  float4 kv = *(const float4*)&kern4[(b * 64 + c) * 4];
  float k0 = kv.x, k1 = kv.y, k2 = kv.z;

  // ---- Phase A: depthwise 3-tap + lrelu -> midT rows [wave*16, wave*16+16)
  {
    float4 q[4] = {q0, q1, q2, q3};
    #pragma unroll
    for (int i = 0; i < 4; ++i) {
      float xa = q[i].x, xb2 = q[i].y, xc = q[i].z, xd = q[i].w;
      float xm1 = hp;
      if (i > 0) xm1 = q[i - 1].w;
      float xp1 = hn;
      if (i < 3) xp1 = q[i + 1].x;
      float m0 = fmaf(k0, xm1, fmaf(k1, xa,  k2 * xb2));
      float m1 = fmaf(k0, xa,  fmaf(k1, xb2, k2 * xc));
      float m2 = fmaf(k0, xb2, fmaf(k1, xc,  k2 * xd));
      float m3 = fmaf(k0, xc,  fmaf(k1, xd,  k2 * xp1));
      int l = wave * 16 + 4 * i;
      midT[(l + 0) * 64 + (c ^ (((l + 0) & 7) << 3))] = f2bf(lrelu(m0));
      midT[(l + 1) * 64 + (c ^ (((l + 1) & 7) << 3))] = f2bf(lrelu(m1));
      midT[(l + 2) * 64 + (c ^ (((l + 2) & 7) << 3))] = f2bf(lrelu(m2));
      midT[(l + 3) * 64 + (c ^ (((l + 3) & 7) << 3))] = f2bf(lrelu(m3));
    }
  }
  // NO barrier: phase B of wave w reads only rows wave wrote itself;
  // compiler inserts the intra-wave lgkmcnt.

  // ---- A-frags: conv_w (pre-converted bf16, L1/L2-resident)
  short8 af[2][4];
  #pragma unroll
  for (int kt = 0; kt < 2; ++kt)
    #pragma unroll
    for (int mt = 0; mt < 4; ++mt)
      af[kt][mt] = *(const short8*)&wfrag[(((kt * 4 + mt) * 64) + lane) * 8];

  // ---- Phase B: out[o][l] = sum_c W[o][c]*mid[c][l] via 16x16x32 bf16 MFMA
  f32x4 acc[4];
  #pragma unroll
  for (int mt = 0; mt < 4; ++mt) acc[mt] = (f32x4){0.f, 0.f, 0.f, 0.f};
  int l = wave * 16 + m_lane;
  #pragma unroll
  for (int kt = 0; kt < 2; ++kt) {
    int cb = kt * 32 + kbase;
    const short8 bf = *(const short8*)&midT[l * 64 + (cb ^ ((l & 7) << 3))];
    #pragma unroll
    for (int mt = 0; mt < 4; ++mt)
      acc[mt] = __builtin_amdgcn_mfma_f32_16x16x32_bf16(af[kt][mt], bf,
                                                        acc[mt], 0, 0, 0);
  }

  // ---- Epilogue: + conv_b + x0*att (x0 re-read, L2-hot), coalesced stores
  {
    int w = wave * 16 + m_lane;
    #pragma unroll
    for (int mt = 0; mt < 4; ++mt) {
      #pragma unroll
      for (int r = 0; r < 4; ++r) {
        int o = mt * 16 + qq * 4 + r;
        float xv = x0[((size_t)(b * 64 + o)) * L_ + l0 + w];
        out[((size_t)(b * 64 + o)) * L_ + l0 + w] =
            acc[mt][r] + conv_b[o] + xv * att[b * 64 + o];
      }
    }
  }
}

extern "C" void kernel_launch(void* const* d_in, const int* in_sizes, int n_in,
                              void* d_out, int out_size, void* d_ws, size_t ws_size,
                              hipStream_t stream) {
  const float* x0     = (const float*)d_in[0];
  const float* x1     = (const float*)d_in[1];
  const float* W1     = (const float*)d_in[2];
  const float* W2     = (const float*)d_in[3];
  const float* conv_w = (const float*)d_in[4];
  const float* conv_b = (const float*)d_in[5];
  const float* ca_w1  = (const float*)d_in[6];
  const float* ca_w2  = (const float*)d_in[7];
  float* out = (float*)d_out;

  float* kern4 = (float*)d_ws;                      // 32*64*4 = 8192 f
  float* att   = kern4 + B_ * C_ * 4;               // 2048 f
  unsigned short* wfrag = (unsigned short*)(att + B_ * C_);  // 4096 bf16

  da_prep<<<dim3(B_), dim3(64), 0, stream>>>(x1, W1, W2, ca_w1, ca_w2, conv_w,
                                             kern4, att, wfrag);
  da_main<<<dim3(NBLK), dim3(256), 0, stream>>>(x0, conv_b, kern4, att, wfrag,
                                                out);
}